// Round 6
// baseline (330.035 us; speedup 1.0000x reference)
//
#include <hip/hip_runtime.h>
#include <hip/hip_bf16.h>
#include <stdint.h>

// Bahdanau attention. B=32, T=2048, D=512, U=512.
// d_out: context[B,D] (16384 f32) then attention_weights[B,T,1] (65536 f32)

#define B_DIM 32
#define T_DIM 2048
#define D_DIM 512
#define U_DIM 512
#define M_DIM (B_DIM * T_DIM)   // 65536 rows

typedef short bf16x8 __attribute__((ext_vector_type(8)));
typedef float f32x4 __attribute__((ext_vector_type(4)));

__device__ __forceinline__ float fast_tanh(float x) {
    float e = __expf(2.0f * x);
    return 1.0f - __fdividef(2.0f, e + 1.0f);
}

// scalar RNE f32->bf16
__device__ __forceinline__ short bf16r(float x) {
    unsigned u = __float_as_uint(x);
    u += 0x7fffu + ((u >> 16) & 1u);
    return (short)(u >> 16);
}

// async global->LDS, 16B per lane (dest = wave-uniform base + lane*16;
// all call sites keep lane-linear LDS addresses). R3/R4/R5-proven correct.
__device__ __forceinline__ void g2lds16(const void* g, void* lds) {
    auto gp = reinterpret_cast<const __attribute__((address_space(1))) unsigned int*>(
        reinterpret_cast<uintptr_t>(g));
    auto lp = reinterpret_cast<__attribute__((address_space(3))) unsigned int*>(
        (unsigned int)(uintptr_t)lds);
    __builtin_amdgcn_global_load_lds(gp, lp, 16, 0, 0);
}

// ---------------------------------------------------------------------------
// Swizzled bf16 layouts (16-byte units = 8 bf16 along k):
//
// VA (values as GEMM A): per (mblock 0..1023, kstep 0..15) a contiguous
//   256-unit (4 KiB) chunk; within: unit = kc*64 + mrow  (kc=0..3, mrow=0..63)
//   element: A[row = mblock*64+mrow][k = kstep*32 + kc*8 + j].
//   Score A-frag read: byte = kc(quad)*1024 + mrow*16 -> 16 consecutive lanes
//   (l15) read 256 contiguous bytes per quad => conflict-free ds_read_b128.
//
// W1T (as GEMM B): per kstep a contiguous 2048-unit (32 KiB) slab; within:
//   unit = kc*512 + u. Frag read: byte = (quad*512 + wc*128 + ui*16 + l15)*16
//   -> 256 contiguous bytes per quad => conflict-free.
// ---------------------------------------------------------------------------

// Kernel 1: prep.
//  blocks [0, 16384): VA convert (1 thread = one 16B unit)
//  blocks [16384, 16512): W1T convert
//  blocks [16512, 16768): qb[b][u] = query[b]@W2_w[:,u] + W2_b[u] + W1_b[u]
//  V_b dropped (softmax shift-invariance).
__global__ void prep_kernel(const float* __restrict__ values,
                            const float* __restrict__ W1_w,
                            const float* __restrict__ W1_b,
                            const float* __restrict__ W2_w,
                            const float* __restrict__ W2_b,
                            const float* __restrict__ query,
                            unsigned short* __restrict__ VA,
                            unsigned short* __restrict__ W1T,
                            float* __restrict__ qb) {
    __shared__ float red[256];
    const int tid = threadIdx.x;
    if (blockIdx.x < 16384) {
        int n = blockIdx.x * 256 + tid;       // unit id 0..4194303
        int mrow   = n & 63;
        int kc     = (n >> 6) & 3;
        int kstep  = (n >> 8) & 15;
        int mblock = n >> 12;
        const float* src = values + (size_t)(mblock * 64 + mrow) * D_DIM
                                  + kstep * 32 + kc * 8;
        float4 f0 = *(const float4*)(src);
        float4 f1 = *(const float4*)(src + 4);
        bf16x8 pk;
        pk[0] = bf16r(f0.x); pk[1] = bf16r(f0.y); pk[2] = bf16r(f0.z); pk[3] = bf16r(f0.w);
        pk[4] = bf16r(f1.x); pk[5] = bf16r(f1.y); pk[6] = bf16r(f1.z); pk[7] = bf16r(f1.w);
        ((bf16x8*)VA)[n] = pk;
    } else if (blockIdx.x < 16512) {
        int n = (blockIdx.x - 16384) * 256 + tid;   // unit id 0..32767
        int u     = n & 511;
        int kc    = (n >> 9) & 3;
        int kstep = n >> 11;
        int k0 = kstep * 32 + kc * 8;
        bf16x8 pk;
#pragma unroll
        for (int j = 0; j < 8; ++j)
            pk[j] = bf16r(W1_w[(size_t)(k0 + j) * U_DIM + u]);  // coalesced in u
        ((bf16x8*)W1T)[n] = pk;
    } else {
        int bid = blockIdx.x - 16512;     // 0..255
        int b  = bid >> 3;
        int ug = bid & 7;
        int u  = ug * 64 + (tid & 63);
        int dq = tid >> 6;                // 0..3 (128 d each)
        const float* q  = query + b * D_DIM + dq * 128;
        const float* w2 = W2_w + (size_t)(dq * 128) * U_DIM + u;
        float acc = 0.f;
#pragma unroll 8
        for (int d = 0; d < 128; ++d)
            acc += q[d] * w2[(size_t)d * U_DIM];
        red[tid] = acc;
        __syncthreads();
        if (tid < 64) {
            qb[b * U_DIM + u] = red[tid] + red[tid + 64] + red[tid + 128]
                              + red[tid + 192] + W2_b[u] + W1_b[u];
        }
    }
}

// ---------------------------------------------------------------------------
// Kernel 2: fused score GEMM, m97-style. 1024 blocks x 512 thr (8 waves).
// Block: 64 m x 512 u (full U -> values read ONCE). Waves: wr=w>>2 (32 m),
// wc=w&3 (128 u). Wave: 2 m-tiles x 8 u-tiles -> 16 f32x4 acc.
// K-loop: A (4 KiB) + B (32 KiB) double-buffered via global_load_lds; the
// loop body is ds_read_b128 + MFMA ONLY (no global loads, no cvt VALU).
// One barrier per BK=32 step.
// ---------------------------------------------------------------------------
__global__ __launch_bounds__(512, 4) void score_kernel(
        const unsigned short* __restrict__ VA,
        const unsigned short* __restrict__ W1T,
        const float* __restrict__ qb,
        const float* __restrict__ Vw,
        float* __restrict__ sP) {
    __shared__ __align__(16) unsigned char smemB[2][32768];
    __shared__ __align__(16) unsigned char smemA[2][4096];

    const int tid  = threadIdx.x;
    const int lane = tid & 63;
    const int w    = tid >> 6;       // 0..7
    const int l15  = lane & 15;
    const int quad = lane >> 4;
    const int wr   = w >> 2;         // 0..1 : 32 m-rows each
    const int wc   = w & 3;          // 0..3 : 128 u each
    const int mb   = blockIdx.x * 64;
    const int b    = mb >> 11;       // 64 | 2048

    const unsigned short* srcA = VA + (size_t)blockIdx.x * 16 * 2048;  // 16 chunks x 256 units x 8
    const unsigned short* srcB = W1T;

    // stage slab 0 (A: threads 0..255 one unit each; B: 4 units per thread)
    if (tid < 256)
        g2lds16(srcA + (size_t)tid * 8, smemA[0] + tid * 16);
#pragma unroll
    for (int i = 0; i < 4; ++i) {
        int unit = i * 512 + tid;    // lane-linear
        g2lds16(srcB + (size_t)unit * 8, smemB[0] + unit * 16);
    }

    f32x4 acc[2][8] = {};

    for (int ks = 0; ks < 16; ++ks) {
        __syncthreads();   // buffers[ks&1] staged (barrier drains vmcnt)

        if (ks < 15) {
            const unsigned short* nA = srcA + (size_t)(ks + 1) * 2048;
            const unsigned short* nB = srcB + (size_t)(ks + 1) * 16384;
            unsigned char* bufA = smemA[(ks + 1) & 1];
            unsigned char* bufB = smemB[(ks + 1) & 1];
            if (tid < 256)
                g2lds16(nA + (size_t)tid * 8, bufA + tid * 16);
#pragma unroll
            for (int i = 0; i < 4; ++i) {
                int unit = i * 512 + tid;
                g2lds16(nB + (size_t)unit * 8, bufB + unit * 16);
            }
        }

        // A fragments: byte = quad*1024 + (wr*32 + mt*16 + l15)*16
        const unsigned char* aB = smemA[ks & 1] + quad * 1024 + (wr * 32 + l15) * 16;
        bf16x8 a0 = *(const bf16x8*)(aB);
        bf16x8 a1 = *(const bf16x8*)(aB + 256);
        // B fragments: byte = (quad*512 + wc*128 + ui*16 + l15)*16
        const unsigned char* bB = smemB[ks & 1] + (size_t)(quad * 512 + wc * 128 + l15) * 16;
#pragma unroll
        for (int ui = 0; ui < 8; ++ui) {
            bf16x8 bf = *(const bf16x8*)(bB + ui * 256);   // 256B-contig/quad
            acc[0][ui] = __builtin_amdgcn_mfma_f32_16x16x32_bf16(a0, bf, acc[0][ui], 0, 0, 0);
            acc[1][ui] = __builtin_amdgcn_mfma_f32_16x16x32_bf16(a1, bf, acc[1][ui], 0, 0, 0);
        }
    }

    // ---- epilogue (once): tanh + Vw, reduce over u ----
    const int ub = wc * 128 + l15;
    float sm[2][4] = {};
#pragma unroll
    for (int ui = 0; ui < 8; ++ui) {
        const int u = ub + ui * 16;
        const float qv = qb[b * U_DIM + u];
        const float vw = Vw[u];
#pragma unroll
        for (int mt = 0; mt < 2; ++mt)
#pragma unroll
            for (int r = 0; r < 4; ++r)
                sm[mt][r] += fast_tanh(acc[mt][ui][r] + qv) * vw;
    }
#pragma unroll
    for (int mt = 0; mt < 2; ++mt)
#pragma unroll
        for (int r = 0; r < 4; ++r) {
            float v = sm[mt][r];
            v += __shfl_xor(v, 1, 64);
            v += __shfl_xor(v, 2, 64);
            v += __shfl_xor(v, 4, 64);
            v += __shfl_xor(v, 8, 64);
            sm[mt][r] = v;
        }
    if (l15 == 0) {
#pragma unroll
        for (int mt = 0; mt < 2; ++mt)
#pragma unroll
            for (int r = 0; r < 4; ++r)
                sP[wc * M_DIM + mb + wr * 32 + mt * 16 + quad * 4 + r] = sm[mt][r];
    }
}

// ---------------------------------------------------------------------------
// Kernel 3: softmax over T per batch; sums the 4 score slices; writes weights.
// ---------------------------------------------------------------------------
__global__ void softmax_kernel(const float* __restrict__ sP,
                               float* __restrict__ out) {
    const int b = blockIdx.x;
    const int tid = threadIdx.x;

    float v[8];
    float mx = -1e30f;
#pragma unroll
    for (int i = 0; i < 8; ++i) {
        int m = b * T_DIM + i * 256 + tid;
        v[i] = sP[m] + sP[M_DIM + m] + sP[2 * M_DIM + m] + sP[3 * M_DIM + m];
        mx = fmaxf(mx, v[i]);
    }
#pragma unroll
    for (int off = 1; off < 64; off <<= 1)
        mx = fmaxf(mx, __shfl_xor(mx, off, 64));
    __shared__ float redm[4];
    if ((tid & 63) == 0) redm[tid >> 6] = mx;
    __syncthreads();
    mx = fmaxf(fmaxf(redm[0], redm[1]), fmaxf(redm[2], redm[3]));

    float sum = 0.f;
#pragma unroll
    for (int i = 0; i < 8; ++i) {
        v[i] = __expf(v[i] - mx);
        sum += v[i];
    }
#pragma unroll
    for (int off = 1; off < 64; off <<= 1)
        sum += __shfl_xor(sum, off, 64);
    __shared__ float reds[4];
    if ((tid & 63) == 0) reds[tid >> 6] = sum;
    __syncthreads();
    sum = reds[0] + reds[1] + reds[2] + reds[3];

    const float inv = 1.0f / sum;
#pragma unroll
    for (int i = 0; i < 8; ++i)
        out[B_DIM * D_DIM + b * T_DIM + i * 256 + tid] = v[i] * inv;
}

// ---------------------------------------------------------------------------
// Kernel 4: context partials. grid (32 tc, 32 b) x 256 thr. Block = 64 t x
// 512 d; two t-interleaved halves combined in LDS; partial -> P (no atomics).
// ---------------------------------------------------------------------------
__global__ void context_kernel(const float* __restrict__ values,
                               const float* __restrict__ weights,
                               float* __restrict__ P) {
    __shared__ float sw[64];
    __shared__ float red[512];
    const int tc = blockIdx.x;   // 0..31 (64 t each)
    const int b  = blockIdx.y;
    const int tid = threadIdx.x;
    const int d4 = tid & 127;    // float4 column
    const int th = tid >> 7;     // t-interleave half

    if (tid < 64) sw[tid] = weights[b * T_DIM + tc * 64 + tid];
    __syncthreads();

    const float4* vb = (const float4*)(values + ((size_t)b * T_DIM + tc * 64) * D_DIM) + d4;
    float4 acc = {0.f, 0.f, 0.f, 0.f};
#pragma unroll 8
    for (int i = th; i < 64; i += 2) {
        float wv = sw[i];
        float4 vv = vb[(size_t)i * 128];
        acc.x += wv * vv.x; acc.y += wv * vv.y;
        acc.z += wv * vv.z; acc.w += wv * vv.w;
    }
    if (th == 1) ((float4*)red)[d4] = acc;
    __syncthreads();
    if (th == 0) {
        float4 o = ((float4*)red)[d4];
        acc.x += o.x; acc.y += o.y; acc.z += o.z; acc.w += o.w;
        *(float4*)(P + ((size_t)(b * 32 + tc)) * 512 + d4 * 4) = acc;
    }
}

// Kernel 5: reduce the 32 t-chunk partials -> context output.
__global__ void reduce_kernel(const float* __restrict__ P,
                              float* __restrict__ ctx) {
    const int g = blockIdx.x * 256 + threadIdx.x;   // 0..16383
    const int b = g >> 9, d = g & 511;
    float s = 0.f;
#pragma unroll
    for (int tc = 0; tc < 32; ++tc)
        s += P[((size_t)(b * 32 + tc)) * 512 + d];
    ctx[g] = s;
}

// ---------------------------------------------------------------------------
extern "C" void kernel_launch(void* const* d_in, const int* in_sizes, int n_in,
                              void* d_out, int out_size, void* d_ws, size_t ws_size,
                              hipStream_t stream) {
    const float* values = (const float*)d_in[0];
    const float* query  = (const float*)d_in[1];
    const float* W1_w   = (const float*)d_in[2];
    const float* W1_b   = (const float*)d_in[3];
    const float* W2_w   = (const float*)d_in[4];
    const float* W2_b   = (const float*)d_in[5];
    const float* V_w    = (const float*)d_in[6];
    // V_b (d_in[7]) dropped: softmax is shift-invariant.

    float* out = (float*)d_out;

    unsigned char* ws = (unsigned char*)d_ws;
    unsigned short* VA  = (unsigned short*)(ws);                 // 64 MiB
    unsigned short* W1T = (unsigned short*)(ws + 67108864);      // 512 KiB
    float* qb = (float*)(ws + 67108864 + 524288);                // 64 KiB
    float* sP = (float*)(ws + 67108864 + 524288 + 65536);        // 1 MiB
    float* P  = (float*)(ws + 67108864 + 524288 + 65536 + 1048576);  // 2 MiB

    prep_kernel<<<16768, 256, 0, stream>>>(values, W1_w, W1_b, W2_w, W2_b,
                                           query, VA, W1T, qb);
    score_kernel<<<1024, 512, 0, stream>>>(VA, W1T, qb, V_w, sP);
    softmax_kernel<<<B_DIM, 256, 0, stream>>>(sP, out);
    context_kernel<<<dim3(32, B_DIM), 256, 0, stream>>>(values, out + B_DIM * D_DIM, P);
    reduce_kernel<<<64, 256, 0, stream>>>(P, out);
}

// Round 7
// 317.389 us; speedup vs baseline: 1.0398x; 1.0398x over previous
//
#include <hip/hip_runtime.h>
#include <hip/hip_bf16.h>
#include <stdint.h>

// Bahdanau attention. B=32, T=2048, D=512, U=512.
// d_out: context[B,D] (16384 f32) then attention_weights[B,T,1] (65536 f32)

#define B_DIM 32
#define T_DIM 2048
#define D_DIM 512
#define U_DIM 512
#define M_DIM (B_DIM * T_DIM)   // 65536 rows

typedef short bf16x8 __attribute__((ext_vector_type(8)));
typedef float f32x4 __attribute__((ext_vector_type(4)));

__device__ __forceinline__ float fast_tanh(float x) {
    float e = __expf(2.0f * x);
    return 1.0f - __fdividef(2.0f, e + 1.0f);
}

// scalar RNE f32->bf16
__device__ __forceinline__ short bf16r(float x) {
    unsigned u = __float_as_uint(x);
    u += 0x7fffu + ((u >> 16) & 1u);
    return (short)(u >> 16);
}

// async global->LDS, 16B per lane (dest = wave-uniform base + lane*16;
// all call sites keep lane-linear LDS addresses). R3..R6-proven correct.
__device__ __forceinline__ void g2lds16(const void* g, void* lds) {
    auto gp = reinterpret_cast<const __attribute__((address_space(1))) unsigned int*>(
        reinterpret_cast<uintptr_t>(g));
    auto lp = reinterpret_cast<__attribute__((address_space(3))) unsigned int*>(
        (unsigned int)(uintptr_t)lds);
    __builtin_amdgcn_global_load_lds(gp, lp, 16, 0, 0);
}

// ---------------------------------------------------------------------------
// Swizzled bf16 layouts (16-byte units = 8 bf16 along k):
//
// VA (values as GEMM A): per (mblock 0..1023, kstep 0..15) a contiguous
//   256-unit (4 KiB) chunk; within: unit = kc*64 + mrow  (kc=0..3, mrow=0..63)
//   element: A[row = mblock*64+mrow][k = kstep*32 + kc*8 + j].
//
// W1T (as GEMM B): per kstep a contiguous 2048-unit (32 KiB) slab; within:
//   unit = kc*512 + u.
// ---------------------------------------------------------------------------

// Kernel 1: prep.
//  blocks [0, 1024): VA convert via LDS transpose — BOTH global sides
//    fully coalesced (R6's direct version gather-read at stride 2048B: 88us).
//  blocks [1024, 1152): W1T convert
//  blocks [1152, 1408): qb[b][u] = query[b]@W2_w[:,u] + W2_b[u] + W1_b[u]
//  V_b dropped (softmax shift-invariance).
#define LSTRIDE 1032   // 64 rows x (1024 B bf16 + 8 pad): 8B-aligned, <=4-way banks
__global__ void prep_kernel(const float* __restrict__ values,
                            const float* __restrict__ W1_w,
                            const float* __restrict__ W1_b,
                            const float* __restrict__ W2_w,
                            const float* __restrict__ W2_b,
                            const float* __restrict__ query,
                            unsigned short* __restrict__ VA,
                            unsigned short* __restrict__ W1T,
                            float* __restrict__ qb) {
    __shared__ __align__(16) unsigned char sm[64 * LSTRIDE];   // 64.5 KiB
    const int tid = threadIdx.x;
    if (blockIdx.x < 1024) {
        const int mb = blockIdx.x;
        const float4* src = (const float4*)(values + (size_t)mb * 64 * D_DIM);
        // phase 1: coalesced read 128 KiB, convert, LDS row-major store
#pragma unroll
        for (int j = 0; j < 32; ++j) {
            int idx = j * 256 + tid;        // float4 id 0..8191
            int row = idx >> 7;             // 0..63
            int dfl = (idx & 127) * 4;      // 0..508
            float4 f = src[idx];
            union { short s[4]; uint2 u; } pk;
            pk.s[0] = bf16r(f.x); pk.s[1] = bf16r(f.y);
            pk.s[2] = bf16r(f.z); pk.s[3] = bf16r(f.w);
            *(uint2*)(sm + row * LSTRIDE + dfl * 2) = pk.u;
        }
        __syncthreads();
        // phase 2: swizzle-gather from LDS, contiguous 64 KiB global write
        uint4* dst = (uint4*)VA + (size_t)mb * 4096;
#pragma unroll
        for (int i = 0; i < 16; ++i) {
            int n = i * 256 + tid;          // unit within chunk set
            int mrow  = n & 63;
            int kc    = (n >> 6) & 3;
            int kstep = n >> 8;
            const unsigned char* p = sm + mrow * LSTRIDE + (kstep * 32 + kc * 8) * 2;
            uint2 lo = *(const uint2*)(p);
            uint2 hi = *(const uint2*)(p + 8);
            uint4 o; o.x = lo.x; o.y = lo.y; o.z = hi.x; o.w = hi.y;
            dst[n] = o;
        }
    } else if (blockIdx.x < 1152) {
        int n = (blockIdx.x - 1024) * 256 + tid;   // unit id 0..32767
        int u     = n & 511;
        int kc    = (n >> 9) & 3;
        int kstep = n >> 11;
        int k0 = kstep * 32 + kc * 8;
        bf16x8 pk;
#pragma unroll
        for (int j = 0; j < 8; ++j)
            pk[j] = bf16r(W1_w[(size_t)(k0 + j) * U_DIM + u]);  // coalesced in u
        ((bf16x8*)W1T)[n] = pk;
    } else {
        float* red = (float*)sm;
        int bid = blockIdx.x - 1152;      // 0..255
        int b  = bid >> 3;
        int ug = bid & 7;
        int u  = ug * 64 + (tid & 63);
        int dq = tid >> 6;                // 0..3 (128 d each)
        const float* q  = query + b * D_DIM + dq * 128;
        const float* w2 = W2_w + (size_t)(dq * 128) * U_DIM + u;
        float acc = 0.f;
#pragma unroll 8
        for (int d = 0; d < 128; ++d)
            acc += q[d] * w2[(size_t)d * U_DIM];
        red[tid] = acc;
        __syncthreads();
        if (tid < 64) {
            qb[b * U_DIM + u] = red[tid] + red[tid + 64] + red[tid + 128]
                              + red[tid + 192] + W2_b[u] + W1_b[u];
        }
    }
}

// ---------------------------------------------------------------------------
// Kernel 2: fused score GEMM, m97-style. 1024 blocks x 512 thr (8 waves).
// Block: 64 m x 512 u (full U -> values read ONCE). Waves: wr=w>>2 (32 m),
// wc=w&3 (128 u). Wave: 2 m-tiles x 8 u-tiles -> 16 f32x4 acc.
// K-loop: A (4 KiB) + B (32 KiB) double-buffered via global_load_lds; the
// loop body is ds_read_b128 + MFMA ONLY (no global loads, no cvt VALU).
// ---------------------------------------------------------------------------
__global__ __launch_bounds__(512, 4) void score_kernel(
        const unsigned short* __restrict__ VA,
        const unsigned short* __restrict__ W1T,
        const float* __restrict__ qb,
        const float* __restrict__ Vw,
        float* __restrict__ sP) {
    __shared__ __align__(16) unsigned char smemB[2][32768];
    __shared__ __align__(16) unsigned char smemA[2][4096];

    const int tid  = threadIdx.x;
    const int lane = tid & 63;
    const int w    = tid >> 6;       // 0..7
    const int l15  = lane & 15;
    const int quad = lane >> 4;
    const int wr   = w >> 2;         // 0..1 : 32 m-rows each
    const int wc   = w & 3;          // 0..3 : 128 u each
    const int mb   = blockIdx.x * 64;
    const int b    = mb >> 11;       // 64 | 2048

    const unsigned short* srcA = VA + (size_t)blockIdx.x * 16 * 2048;
    const unsigned short* srcB = W1T;

    if (tid < 256)
        g2lds16(srcA + (size_t)tid * 8, smemA[0] + tid * 16);
#pragma unroll
    for (int i = 0; i < 4; ++i) {
        int unit = i * 512 + tid;    // lane-linear
        g2lds16(srcB + (size_t)unit * 8, smemB[0] + unit * 16);
    }

    f32x4 acc[2][8] = {};

    for (int ks = 0; ks < 16; ++ks) {
        __syncthreads();   // buffers[ks&1] staged (barrier drains vmcnt)

        if (ks < 15) {
            const unsigned short* nA = srcA + (size_t)(ks + 1) * 2048;
            const unsigned short* nB = srcB + (size_t)(ks + 1) * 16384;
            unsigned char* bufA = smemA[(ks + 1) & 1];
            unsigned char* bufB = smemB[(ks + 1) & 1];
            if (tid < 256)
                g2lds16(nA + (size_t)tid * 8, bufA + tid * 16);
#pragma unroll
            for (int i = 0; i < 4; ++i) {
                int unit = i * 512 + tid;
                g2lds16(nB + (size_t)unit * 8, bufB + unit * 16);
            }
        }

        const unsigned char* aB = smemA[ks & 1] + quad * 1024 + (wr * 32 + l15) * 16;
        bf16x8 a0 = *(const bf16x8*)(aB);
        bf16x8 a1 = *(const bf16x8*)(aB + 256);
        const unsigned char* bB = smemB[ks & 1] + (size_t)(quad * 512 + wc * 128 + l15) * 16;
#pragma unroll
        for (int ui = 0; ui < 8; ++ui) {
            bf16x8 bf = *(const bf16x8*)(bB + ui * 256);   // 256B-contig/quad
            acc[0][ui] = __builtin_amdgcn_mfma_f32_16x16x32_bf16(a0, bf, acc[0][ui], 0, 0, 0);
            acc[1][ui] = __builtin_amdgcn_mfma_f32_16x16x32_bf16(a1, bf, acc[1][ui], 0, 0, 0);
        }
    }

    // ---- epilogue (once): tanh + Vw, reduce over u ----
    const int ub = wc * 128 + l15;
    float sm_[2][4] = {};
#pragma unroll
    for (int ui = 0; ui < 8; ++ui) {
        const int u = ub + ui * 16;
        const float qv = qb[b * U_DIM + u];
        const float vw = Vw[u];
#pragma unroll
        for (int mt = 0; mt < 2; ++mt)
#pragma unroll
            for (int r = 0; r < 4; ++r)
                sm_[mt][r] += fast_tanh(acc[mt][ui][r] + qv) * vw;
    }
#pragma unroll
    for (int mt = 0; mt < 2; ++mt)
#pragma unroll
        for (int r = 0; r < 4; ++r) {
            float v = sm_[mt][r];
            v += __shfl_xor(v, 1, 64);
            v += __shfl_xor(v, 2, 64);
            v += __shfl_xor(v, 4, 64);
            v += __shfl_xor(v, 8, 64);
            sm_[mt][r] = v;
        }
    if (l15 == 0) {
#pragma unroll
        for (int mt = 0; mt < 2; ++mt)
#pragma unroll
            for (int r = 0; r < 4; ++r)
                sP[wc * M_DIM + mb + wr * 32 + mt * 16 + quad * 4 + r] = sm_[mt][r];
    }
}

// ---------------------------------------------------------------------------
// Kernel 3: softmax over T per batch; sums the 4 score slices; writes weights.
// ---------------------------------------------------------------------------
__global__ void softmax_kernel(const float* __restrict__ sP,
                               float* __restrict__ out) {
    const int b = blockIdx.x;
    const int tid = threadIdx.x;

    float v[8];
    float mx = -1e30f;
#pragma unroll
    for (int i = 0; i < 8; ++i) {
        int m = b * T_DIM + i * 256 + tid;
        v[i] = sP[m] + sP[M_DIM + m] + sP[2 * M_DIM + m] + sP[3 * M_DIM + m];
        mx = fmaxf(mx, v[i]);
    }
#pragma unroll
    for (int off = 1; off < 64; off <<= 1)
        mx = fmaxf(mx, __shfl_xor(mx, off, 64));
    __shared__ float redm[4];
    if ((tid & 63) == 0) redm[tid >> 6] = mx;
    __syncthreads();
    mx = fmaxf(fmaxf(redm[0], redm[1]), fmaxf(redm[2], redm[3]));

    float sum = 0.f;
#pragma unroll
    for (int i = 0; i < 8; ++i) {
        v[i] = __expf(v[i] - mx);
        sum += v[i];
    }
#pragma unroll
    for (int off = 1; off < 64; off <<= 1)
        sum += __shfl_xor(sum, off, 64);
    __shared__ float reds[4];
    if ((tid & 63) == 0) reds[tid >> 6] = sum;
    __syncthreads();
    sum = reds[0] + reds[1] + reds[2] + reds[3];

    const float inv = 1.0f / sum;
#pragma unroll
    for (int i = 0; i < 8; ++i)
        out[B_DIM * D_DIM + b * T_DIM + i * 256 + tid] = v[i] * inv;
}

// ---------------------------------------------------------------------------
// Kernel 4: context partials. grid (32 tc, 32 b) x 256 thr. Block = 64 t x
// 512 d; two t-interleaved halves combined in LDS; partial -> P (no atomics).
// ---------------------------------------------------------------------------
__global__ void context_kernel(const float* __restrict__ values,
                               const float* __restrict__ weights,
                               float* __restrict__ P) {
    __shared__ float sw[64];
    __shared__ float red[512];
    const int tc = blockIdx.x;   // 0..31 (64 t each)
    const int b  = blockIdx.y;
    const int tid = threadIdx.x;
    const int d4 = tid & 127;    // float4 column
    const int th = tid >> 7;     // t-interleave half

    if (tid < 64) sw[tid] = weights[b * T_DIM + tc * 64 + tid];
    __syncthreads();

    const float4* vb = (const float4*)(values + ((size_t)b * T_DIM + tc * 64) * D_DIM) + d4;
    float4 acc = {0.f, 0.f, 0.f, 0.f};
#pragma unroll 8
    for (int i = th; i < 64; i += 2) {
        float wv = sw[i];
        float4 vv = vb[(size_t)i * 128];
        acc.x += wv * vv.x; acc.y += wv * vv.y;
        acc.z += wv * vv.z; acc.w += wv * vv.w;
    }
    if (th == 1) ((float4*)red)[d4] = acc;
    __syncthreads();
    if (th == 0) {
        float4 o = ((float4*)red)[d4];
        acc.x += o.x; acc.y += o.y; acc.z += o.z; acc.w += o.w;
        *(float4*)(P + ((size_t)(b * 32 + tc)) * 512 + d4 * 4) = acc;
    }
}

// Kernel 5: reduce the 32 t-chunk partials -> context output.
__global__ void reduce_kernel(const float* __restrict__ P,
                              float* __restrict__ ctx) {
    const int g = blockIdx.x * 256 + threadIdx.x;   // 0..16383
    const int b = g >> 9, d = g & 511;
    float s = 0.f;
#pragma unroll
    for (int tc = 0; tc < 32; ++tc)
        s += P[((size_t)(b * 32 + tc)) * 512 + d];
    ctx[g] = s;
}

// ---------------------------------------------------------------------------
extern "C" void kernel_launch(void* const* d_in, const int* in_sizes, int n_in,
                              void* d_out, int out_size, void* d_ws, size_t ws_size,
                              hipStream_t stream) {
    const float* values = (const float*)d_in[0];
    const float* query  = (const float*)d_in[1];
    const float* W1_w   = (const float*)d_in[2];
    const float* W1_b   = (const float*)d_in[3];
    const float* W2_w   = (const float*)d_in[4];
    const float* W2_b   = (const float*)d_in[5];
    const float* V_w    = (const float*)d_in[6];
    // V_b (d_in[7]) dropped: softmax is shift-invariant.

    float* out = (float*)d_out;

    unsigned char* ws = (unsigned char*)d_ws;
    unsigned short* VA  = (unsigned short*)(ws);                 // 64 MiB
    unsigned short* W1T = (unsigned short*)(ws + 67108864);      // 512 KiB
    float* qb = (float*)(ws + 67108864 + 524288);                // 64 KiB
    float* sP = (float*)(ws + 67108864 + 524288 + 65536);        // 1 MiB
    float* P  = (float*)(ws + 67108864 + 524288 + 65536 + 1048576);  // 2 MiB

    prep_kernel<<<1408, 256, 0, stream>>>(values, W1_w, W1_b, W2_w, W2_b,
                                          query, VA, W1T, qb);
    score_kernel<<<1024, 512, 0, stream>>>(VA, W1T, qb, V_w, sP);
    softmax_kernel<<<B_DIM, 256, 0, stream>>>(sP, out);
    context_kernel<<<dim3(32, B_DIM), 256, 0, stream>>>(values, out + B_DIM * D_DIM, P);
    reduce_kernel<<<64, 256, 0, stream>>>(P, out);
}